// Round 13
// baseline (101.856 us; speedup 1.0000x reference)
//
#include <hip/hip_runtime.h>
#include <math.h>

#define Bq 128
#define Nn 8
#define LQ 32
#define LD 256
#define DD 128
#define EPSN 1e-12f
#define NEGV (-9999.0f)

typedef __attribute__((ext_vector_type(8))) short short8v;
typedef __attribute__((ext_vector_type(4))) int   int4v;
typedef __attribute__((ext_vector_type(4))) float f32x4;

__device__ __forceinline__ unsigned bf16_rne_hibits(float x) {
    unsigned u = __float_as_uint(x);
    return (u + 0x7FFFu + ((u >> 16) & 1u)) & 0xFFFF0000u;
}

// ---------------- Kernel 1: normalize q rows, emit SWIZZLED bf16 planes ----
// (round 12, verified): 16B chunk c -> c ^ (row&7) within each 256B row;
// maxsim stages linearly to LDS and reads with the same XOR -> conflict-free.
__global__ __launch_bounds__(256) void qnorm_k(const float* __restrict__ q,
                                               unsigned short* __restrict__ qh,
                                               unsigned short* __restrict__ ql) {
    int row  = blockIdx.x * 4 + (threadIdx.x >> 6);   // 4096 rows = [B][LQ]
    int lane = threadIdx.x & 63;
    size_t base = (size_t)row * DD + lane * 2;
    float2 v = *reinterpret_cast<const float2*>(q + base);
    float ss = v.x * v.x + v.y * v.y;
#pragma unroll
    for (int o = 32; o; o >>= 1) ss += __shfl_xor(ss, o);
    float inv = 1.0f / fmaxf(sqrtf(ss), EPSN);
    float x0 = v.x * inv, x1 = v.y * inv;
    unsigned h0 = bf16_rne_hibits(x0), h1 = bf16_rne_hibits(x1);
    float l0 = x0 - __uint_as_float(h0);
    float l1 = x1 - __uint_as_float(h1);
    unsigned g0 = bf16_rne_hibits(l0), g1 = bf16_rne_hibits(l1);
    unsigned swz = ((unsigned)(lane * 2)) ^ (((unsigned)row & 7u) << 3);
    *reinterpret_cast<unsigned*>(qh + (size_t)row * DD + swz) = (h0 >> 16) | h1;
    *reinterpret_cast<unsigned*>(ql + (size_t)row * DD + swz) = (g0 >> 16) | g1;
}

// ---------------- Kernel 2: MaxSim via MFMA, occupancy-first ----------------
// Round-13: back to single-tensor blocks (grid 2048 = 8 blocks/CU) with a
// GENUINELY 64-feasible live set so __launch_bounds__(256,8) gives 8 waves/
// SIMD (rounds 8/9 needed ~72 and spilled; since then: LDS A-frags -8 regs,
// trunc-cvt -4, and NEW halved A-liveness -8):
//   KSTEP = cvt(d) -> prefetch d(+2) -> a0 ds_reads -> 3 c0-MFMAs -> SB ->
//           a1 ds_reads -> 3 c1-MFMAs       (peak A-regs 8, not 16)
// Live count: d ping-pong 16 + dhw/dlw 8 + A 8 + c 8 + rm 8 + prow 2 +
// misc ~10 = ~60 < 64.  Spill signature to check: VGPR~32 + WRITE>60MB.
__global__ __launch_bounds__(256, 8) void maxsim_k(const float* __restrict__ d_cq,
                                                   const float* __restrict__ d_orig,
                                                   const int* __restrict__ mask,
                                                   const unsigned short* __restrict__ qh,
                                                   const unsigned short* __restrict__ ql,
                                                   float* __restrict__ scores) {
    __shared__ float4 qstage[1024];   // 16KB: [0,512)=qh plane, [512,1024)=ql
    __shared__ float wm[4][32];

    int bid = blockIdx.x;             // [0, 2048)
    int tau = bid >> 10;              // 0 = cq (student), 1 = orig (teacher)
    int nb  = bid & 1023;             // n*Bq + b
    int b   = nb & 127;
    int n   = nb >> 7;

    int tid  = threadIdx.x;
    int w    = tid >> 6;              // wave id: d-rows [w*64, w*64+64)
    int lane = tid & 63;
    int r    = lane & 15;             // B-frag col / C col (local d-row)
    int g    = lane >> 4;             // k-group (8 elems each)

    {   // stage swizzled q planes -> LDS (linear copy preserves swizzle)
        const float4* srch = reinterpret_cast<const float4*>(qh + (size_t)b * LQ * DD);
        const float4* srcl = reinterpret_cast<const float4*>(ql + (size_t)b * LQ * DD);
        qstage[tid]       = srch[tid];
        qstage[tid + 256] = srch[tid + 256];
        qstage[tid + 512] = srcl[tid];
        qstage[tid + 768] = srcl[tid + 256];
    }
    __syncthreads();

    const unsigned short* qh_lds = reinterpret_cast<const unsigned short*>(qstage);
    const unsigned short* ql_lds = qh_lds + LQ * DD;
    unsigned swz8 = ((unsigned)r & 7u) << 3;   // read-side XOR (elem units)

    f32x4 rm0 = {NEGV, NEGV, NEGV, NEGV};
    f32x4 rm1 = {NEGV, NEGV, NEGV, NEGV};

#define SB __builtin_amdgcn_sched_barrier(0)

// truncation hi/lo split (round-8/12 verified: absmax 0.0)
#define CVT2(W, X0, X1)                                                        \
    { unsigned u0 = __float_as_uint(X0), u1 = __float_as_uint(X1);             \
      dhw[W] = (int)((u0 >> 16) | (u1 & 0xFFFF0000u));                         \
      float l0 = (X0) - __uint_as_float(u0 & 0xFFFF0000u);                     \
      float l1 = (X1) - __uint_as_float(u1 & 0xFFFF0000u);                     \
      dlw[W] = (int)((__float_as_uint(l0) >> 16) |                             \
                    (__float_as_uint(l1) & 0xFFFF0000u));                      \
      ssq += (X0)*(X0) + (X1)*(X1); }

// Consume (C0,C1); prefetch PFOFF back into them (WAR-safe by program
// order); A-frags from swizzled LDS in TWO halves to cap liveness at 8.
#define KSTEP(C0, C1, KS, PFOFF)                                               \
    {                                                                          \
        int4v dhw, dlw;                                                        \
        CVT2(0, C0.x, C0.y) CVT2(1, C0.z, C0.w)                                \
        CVT2(2, C1.x, C1.y) CVT2(3, C1.z, C1.w)                                \
        C0 = *reinterpret_cast<const float4*>(prow + (PFOFF));                 \
        C1 = *reinterpret_cast<const float4*>(prow + (PFOFF) + 4);             \
        short8v dh = __builtin_bit_cast(short8v, dhw);                         \
        short8v dl = __builtin_bit_cast(short8v, dlw);                         \
        unsigned aoff = (((unsigned)(KS) * 32u) + (unsigned)g * 8u) ^ swz8;    \
        short8v a0h = *reinterpret_cast<const short8v*>(qh_lds + r * DD + aoff);        \
        short8v a0l = *reinterpret_cast<const short8v*>(ql_lds + r * DD + aoff);        \
        c0 = __builtin_amdgcn_mfma_f32_16x16x32_bf16(a0h, dh, c0, 0, 0, 0);    \
        c0 = __builtin_amdgcn_mfma_f32_16x16x32_bf16(a0h, dl, c0, 0, 0, 0);    \
        c0 = __builtin_amdgcn_mfma_f32_16x16x32_bf16(a0l, dh, c0, 0, 0, 0);    \
        SB;                                                                    \
        short8v a1h = *reinterpret_cast<const short8v*>(qh_lds + (r + 16) * DD + aoff); \
        short8v a1l = *reinterpret_cast<const short8v*>(ql_lds + (r + 16) * DD + aoff); \
        c1 = __builtin_amdgcn_mfma_f32_16x16x32_bf16(a1h, dh, c1, 0, 0, 0);    \
        c1 = __builtin_amdgcn_mfma_f32_16x16x32_bf16(a1h, dl, c1, 0, 0, 0);    \
        c1 = __builtin_amdgcn_mfma_f32_16x16x32_bf16(a1l, dh, c1, 0, 0, 0);    \
    }

    const float* prow = (tau ? d_orig : d_cq)
        + (size_t)nb * (LD * DD) + (size_t)(w * 64 + r) * DD + g * 8;

    // steady-state pipeline: X holds ks0, Y holds ks1 at nt-loop top
    float4 X0 = *reinterpret_cast<const float4*>(prow);
    float4 X1 = *reinterpret_cast<const float4*>(prow + 4);
    float4 Y0 = *reinterpret_cast<const float4*>(prow + 32);
    float4 Y1 = *reinterpret_cast<const float4*>(prow + 36);

#pragma unroll 1
    for (int nt = 0; nt < 4; ++nt) {
        int drow = w * 64 + nt * 16 + r;

        f32x4 c0 = {0.f, 0.f, 0.f, 0.f};
        f32x4 c1 = {0.f, 0.f, 0.f, 0.f};
        float ssq = 0.0f;

        int mk = mask[(size_t)nb * LD + drow];    // early, in flight
        int nnoff = (nt < 3) ? 2048 : 0;          // next-nt (16 rows) or clamp

        KSTEP(X0, X1, 0, 64);          SB;        // fetch ks2 -> X
        KSTEP(Y0, Y1, 1, 96);          SB;        // fetch ks3 -> Y
        KSTEP(X0, X1, 2, nnoff);       SB;        // fetch next-nt ks0 -> X
        KSTEP(Y0, Y1, 3, nnoff + 32);  SB;        // fetch next-nt ks1 -> Y

        // full row ssq: lane covers k = ks*32 + g*8 + e; combine 4 g-lanes
        ssq += __shfl_xor(ssq, 16);
        ssq += __shfl_xor(ssq, 32);
        float inv = 1.0f / fmaxf(sqrtf(ssq), EPSN);

        // C layout: col = lane&15 = local d-row; row(lq) = g*4+i (+16 for c1)
#pragma unroll
        for (int i = 0; i < 4; ++i) {
            rm0[i] = fmaxf(rm0[i], mk ? c0[i] * inv : NEGV);
            rm1[i] = fmaxf(rm1[i], mk ? c1[i] * inv : NEGV);
        }
        prow += 16 * DD;
    }
#undef KSTEP
#undef CVT2

    // max over the wave's 64 d-rows: reduce across the 16 cols (lane&15)
#pragma unroll
    for (int i = 0; i < 4; ++i) {
#pragma unroll
        for (int o = 1; o <= 8; o <<= 1) {
            rm0[i] = fmaxf(rm0[i], __shfl_xor(rm0[i], o));
            rm1[i] = fmaxf(rm1[i], __shfl_xor(rm1[i], o));
        }
    }
    if (r == 0) {
#pragma unroll
        for (int i = 0; i < 4; ++i) {
            wm[w][g * 4 + i]      = rm0[i];
            wm[w][16 + g * 4 + i] = rm1[i];
        }
    }
    __syncthreads();

    if (tid < 32) {   // lane = lq
        float v = fmaxf(fmaxf(wm[0][tid], wm[1][tid]),
                        fmaxf(wm[2][tid], wm[3][tid]));
#pragma unroll
        for (int o = 1; o <= 16; o <<= 1) v += __shfl_xor(v, o);
        if (tid == 0)
            scores[tau * (Bq * Nn) + b * Nn + n] = v;
    }
}

// ---------------- Kernel 3: log_softmax + KL ----------------
__global__ void loss_k(const float* __restrict__ scores, float* __restrict__ out) {
    int tid = threadIdx.x;   // 128 threads, one per b
    const float* s = scores + tid * Nn;            // student (cq)
    const float* t = scores + Bq * Nn + tid * Nn;  // teacher (orig)
    float sv[Nn], tv[Nn];
#pragma unroll
    for (int n = 0; n < Nn; ++n) { sv[n] = s[n]; tv[n] = t[n]; }
    float ms = sv[0], mt = tv[0];
#pragma unroll
    for (int n = 1; n < Nn; ++n) { ms = fmaxf(ms, sv[n]); mt = fmaxf(mt, tv[n]); }
    float es = 0.0f, et = 0.0f;
#pragma unroll
    for (int n = 0; n < Nn; ++n) { es += expf(sv[n] - ms); et += expf(tv[n] - mt); }
    float lses = ms + logf(es);
    float lset = mt + logf(et);
    double kl = 0.0;
#pragma unroll
    for (int n = 0; n < Nn; ++n) {
        float lt = tv[n] - lset;
        float ls = sv[n] - lses;
        kl += (double)expf(lt) * ((double)lt - (double)ls);
    }
#pragma unroll
    for (int o = 32; o; o >>= 1) kl += __shfl_xor(kl, o);
    __shared__ double part[2];
    if ((tid & 63) == 0) part[tid >> 6] = kl;
    __syncthreads();
    if (tid == 0) out[0] = (float)((part[0] + part[1]) / (double)Bq);
}

extern "C" void kernel_launch(void* const* d_in, const int* in_sizes, int n_in,
                              void* d_out, int out_size, void* d_ws, size_t ws_size,
                              hipStream_t stream) {
    const float* q     = (const float*)d_in[0];
    const float* dcq   = (const float*)d_in[1];
    const float* dorig = (const float*)d_in[2];
    const int*   mask  = (const int*)d_in[3];
    // labels (d_in[4]) unused by the reference loss path

    unsigned short* qh = (unsigned short*)d_ws;                  // [B][32][128] bf16-hi (swizzled rows), 1MB
    unsigned short* ql = qh + (size_t)Bq * LQ * DD;              // bf16-lo (swizzled rows), 1MB
    float* scores      = (float*)(ql + (size_t)Bq * LQ * DD);    // [2][B][N], 8KB

    qnorm_k<<<(Bq * LQ) / 4, 256, 0, stream>>>(q, qh, ql);
    maxsim_k<<<2 * Nn * Bq, 256, 0, stream>>>(dcq, dorig, mask, qh, ql, scores);
    loss_k<<<1, 128, 0, stream>>>(scores, (float*)d_out);
}